// Round 8
// baseline (291.915 us; speedup 1.0000x reference)
//
#include <hip/hip_runtime.h>

#define N_NODES 50000
#define N_EDGES 800000
#define D_HID   128

typedef unsigned int uint;
typedef unsigned short ushort;
typedef __attribute__((ext_vector_type(8))) short short8;
typedef __attribute__((ext_vector_type(4))) float f32x4;

#define SCAN_NB ((N_NODES + 255) / 256)   // 196

// ---------------- degree count ----------------
__global__ void deg_count_k(const int* __restrict__ dst, int* __restrict__ cnt, int e) {
    int i = blockIdx.x * 256 + threadIdx.x;
    if (i < e) atomicAdd(&cnt[dst[i]], 1);
}

// ---------------- 3-phase multi-block exclusive scan ----------------
__global__ void bsum_k(const int* __restrict__ cnt, int* __restrict__ bsum, int n) {
    int i = blockIdx.x * 256 + threadIdx.x;
    int v = (i < n) ? cnt[i] : 0;
#pragma unroll
    for (int off = 32; off; off >>= 1) v += __shfl_down(v, off, 64);
    __shared__ int ws[4];
    int lane = threadIdx.x & 63, w = threadIdx.x >> 6;
    if (lane == 0) ws[w] = v;
    __syncthreads();
    if (threadIdx.x == 0) bsum[blockIdx.x] = ws[0] + ws[1] + ws[2] + ws[3];
}

__global__ void bscan_k(const int* __restrict__ bsum, int* __restrict__ boff,
                        int* __restrict__ row_ptr_end, int nb) {
    __shared__ int s[256];
    int t = threadIdx.x;
    int v = (t < nb) ? bsum[t] : 0;
    s[t] = v;
    __syncthreads();
    for (int off = 1; off < 256; off <<= 1) {
        int u = (t >= off) ? s[t - off] : 0;
        __syncthreads();
        s[t] += u;
        __syncthreads();
    }
    if (t < nb) boff[t] = s[t] - v;        // exclusive
    if (t == 255) *row_ptr_end = s[255];   // total -> row_ptr[n]
}

// scan + fused degree-norm + cursor zeroing
__global__ void scan3_k(const int* __restrict__ cnt, const int* __restrict__ boff,
                        int* __restrict__ row_ptr, float* __restrict__ dis,
                        float* __restrict__ dinv, int* __restrict__ cursor, int n) {
    __shared__ int s[256];
    int i = blockIdx.x * 256 + threadIdx.x;
    int t = threadIdx.x;
    int v = (i < n) ? cnt[i] : 0;
    s[t] = v;
    __syncthreads();
    for (int off = 1; off < 256; off <<= 1) {
        int u = (t >= off) ? s[t - off] : 0;
        __syncthreads();
        s[t] += u;
        __syncthreads();
    }
    if (i < n) {
        row_ptr[i] = boff[blockIdx.x] + s[t] - v;
        float d = (float)v + 1.0f;
        dis[i]  = rsqrtf(d);
        dinv[i] = 1.0f / d;
        cursor[i] = 0;
    }
}

// ---------------- scatter edges into CSR (col only) ----------------
__global__ void scatter_k(const int* __restrict__ src, const int* __restrict__ dst,
                          const int* __restrict__ row_ptr, int* __restrict__ cursor,
                          int* __restrict__ col, int e) {
    int i = blockIdx.x * 256 + threadIdx.x;
    if (i < e) {
        int s = src[i], d = dst[i];
        int pos = row_ptr[d] + atomicAdd(&cursor[d], 1);
        col[pos] = s;
    }
}

// ---------------- canonicalize CSR rows: sort each row's col segment ----------------
// Atomic scatter order is nondeterministic across calls; a sorted row is a
// canonical representation (duplicate src entries are interchangeable), making
// every downstream fp32 sum bit-deterministic call-to-call.
__global__ __launch_bounds__(256) void sortrow_k(const int* __restrict__ rp,
                                                 int* __restrict__ col, int n) {
    int node = blockIdx.x * 4 + (threadIdx.x >> 6);
    if (node >= n) return;
    int lane = threadIdx.x & 63;
    int beg = rp[node], end = rp[node + 1];
    int len = end - beg;
    if (len <= 1) return;
    if (len <= 64) {
        int v = (lane < len) ? col[beg + lane] : 0x7fffffff;
        for (int k = 2; k <= 64; k <<= 1) {
            for (int j = k >> 1; j > 0; j >>= 1) {
                int other = __shfl_xor(v, j);
                bool up    = (lane & k) == 0;     // segment direction (k=64: all asc)
                bool small = (lane & j) == 0;     // lane < partner
                v = (small == up) ? min(v, other) : max(v, other);
            }
        }
        if (lane < len) col[beg + lane] = v;
    } else if (lane == 0) {     // rare tail: serial insertion sort
        for (int i = beg + 1; i < end; ++i) {
            int key = col[i]; int j = i - 1;
            while (j >= beg && col[j] > key) { col[j + 1] = col[j]; --j; }
            col[j + 1] = key;
        }
    }
}

// ---- fp32 -> bf16 (RTNE) ----
__device__ inline ushort f2bf(float f) {
    unsigned u = __float_as_uint(f);
    unsigned rounding = 0x7fffu + ((u >> 16) & 1u);
    return (ushort)((u + rounding) >> 16);
}
__device__ inline float bf_lo(uint v) { return __uint_as_float(v << 16); }
__device__ inline float bf_hi(uint v) { return __uint_as_float(v & 0xffff0000u); }
__device__ inline short8 cvt8(float4 f0, float4 f1) {
    short8 r;
    r[0] = (short)f2bf(f0.x); r[1] = (short)f2bf(f0.y);
    r[2] = (short)f2bf(f0.z); r[3] = (short)f2bf(f0.w);
    r[4] = (short)f2bf(f1.x); r[5] = (short)f2bf(f1.y);
    r[6] = (short)f2bf(f1.z); r[7] = (short)f2bf(f1.w);
    return r;
}

// ---------------- all three W[K][128] fp32 -> Wt[128][K] bf16, one launch ----------------
__global__ void wtrans_all_k(const float* __restrict__ W0, const float* __restrict__ W1,
                             const float* __restrict__ W2, ushort* __restrict__ Wt0,
                             ushort* __restrict__ Wt1, ushort* __restrict__ Wt2) {
    int i = blockIdx.x * 256 + threadIdx.x;   // 0..65535
    const float* W; ushort* Wt; int K, j;
    if (i < 32768)      { W = W0; Wt = Wt0; K = 256; j = i; }
    else if (i < 49152) { W = W1; Wt = Wt1; K = 128; j = i - 32768; }
    else                { W = W2; Wt = Wt2; K = 128; j = i - 49152; }
    int k = j >> 7, n = j & 127;
    Wt[(size_t)n * K + k] = f2bf(W[j]);
}

// ---------------- MFMA GEMM, register-resident B, tile loop + A prefetch ----------------
// K=128: tile 32 rows; wave: rows (w>>1)*16, cols (w&1)*64 (NC=4, T=4)
// K=256: tile 16 rows; wave: all rows, cols w*32 (NC=2, T=8)
template<int K, bool AF32>
__global__ __launch_bounds__(256, 3) void mfma_gemm_k(const void* __restrict__ Ap,
                                                      const ushort* __restrict__ Bt, // [128][K]
                                                      ushort* __restrict__ H,        // [M][128]
                                                      int M, int ntiles) {
    constexpr int T   = K / 32;
    constexpr int NC  = (K == 128) ? 4 : 2;
    constexpr int RPT = (K == 128) ? 32 : 16;
    int tid = threadIdx.x;
    int w = tid >> 6, l = tid & 63;
    int lr = l & 15, kg = (l >> 4) * 8;
    int rIn   = (K == 128) ? (w >> 1) * 16 : 0;
    int cBase = (K == 128) ? (w & 1) * 64 : w * 32;

    // B-fragments resident in registers, loaded once per block
    short8 b[NC][T];
#pragma unroll
    for (int c = 0; c < NC; ++c)
#pragma unroll
        for (int t = 0; t < T; ++t)
            b[c][t] = *(const short8*)&Bt[(size_t)(cBase + c * 16 + lr) * K + t * 32 + kg];

    int tile = blockIdx.x;
    if (tile >= ntiles) return;
    const int G = gridDim.x;

    auto loadA = [&](int tl, short8* dst) {
        int rc = tl * RPT + rIn + lr; if (rc >= M) rc = M - 1;
        if constexpr (AF32) {
            const float* A32 = (const float*)Ap;
#pragma unroll
            for (int t = 0; t < T; ++t) {
                float4 f0 = *(const float4*)&A32[(size_t)rc * K + t * 32 + kg];
                float4 f1 = *(const float4*)&A32[(size_t)rc * K + t * 32 + kg + 4];
                dst[t] = cvt8(f0, f1);
            }
        } else {
            const ushort* A16 = (const ushort*)Ap;
#pragma unroll
            for (int t = 0; t < T; ++t)
                dst[t] = *(const short8*)&A16[(size_t)rc * K + t * 32 + kg];
        }
    };

    short8 a[T];
    loadA(tile, a);
    for (; tile < ntiles; tile += G) {
        short8 an[T];
        int nt = tile + G;
        if (nt < ntiles) loadA(nt, an);          // prefetch next tile's A

        f32x4 acc[NC];
#pragma unroll
        for (int c = 0; c < NC; ++c) acc[c] = (f32x4){0.f, 0.f, 0.f, 0.f};
#pragma unroll
        for (int t = 0; t < T; ++t)
#pragma unroll
            for (int c = 0; c < NC; ++c)
                acc[c] = __builtin_amdgcn_mfma_f32_16x16x32_bf16(a[t], b[c][t], acc[c], 0, 0, 0);

        int rs = tile * RPT + rIn + (l >> 4) * 4;
#pragma unroll
        for (int c = 0; c < NC; ++c)
#pragma unroll
            for (int j = 0; j < 4; ++j) {
                int r = rs + j;
                if (r < M) H[(size_t)r * 128 + cBase + c * 16 + lr] = f2bf(acc[c][j]);
            }
#pragma unroll
        for (int t = 0; t < T; ++t) a[t] = an[t];
    }
}

// ---------------- aggregate: relu(dis[n]*sum_e(dis[s]*hb[s]) + hb[n]*dinv[n] + b) ----------------
// uint4 gathers: 16 lanes cover one 256B row -> 4 edges in flight per load instruction.
template<bool LAST>
__global__ __launch_bounds__(256) void aggregate_k(const ushort* __restrict__ hb,
                                                   const int* __restrict__ row_ptr,
                                                   const int* __restrict__ col,
                                                   const float* __restrict__ dis,
                                                   const float* __restrict__ dinv,
                                                   const float* __restrict__ bias,
                                                   ushort* __restrict__ act,
                                                   float* __restrict__ out, int n) {
    int node = blockIdx.x * 4 + (threadIdx.x >> 6);
    if (node >= n) return;
    int lane = threadIdx.x & 63;
    int g  = lane >> 4;          // edge-slot group 0..3
    int cl = lane & 15;          // column block: cols [8*cl, 8*cl+8)
    const char* base = (const char*)hb + (cl << 4);   // cl*16 bytes within row

    float ax[8];
#pragma unroll
    for (int j = 0; j < 8; ++j) ax[j] = 0.f;

    int beg = row_ptr[node], end = row_ptr[node + 1];
    for (int e = beg; e < end; e += 16) {
        int s[4]; float wv[4];
#pragma unroll
        for (int q = 0; q < 4; ++q) {
            int idx = e + q * 4 + g;
            bool v  = idx < end;
            s[q]  = col[v ? idx : (end - 1)];
            wv[q] = v ? dis[s[q]] : 0.f;
        }
        uint4 u[4];
#pragma unroll
        for (int q = 0; q < 4; ++q)
            u[q] = *(const uint4*)(base + ((size_t)s[q] << 8));
#pragma unroll
        for (int q = 0; q < 4; ++q) {
            float ww = wv[q];
            ax[0] += ww * bf_lo(u[q].x); ax[1] += ww * bf_hi(u[q].x);
            ax[2] += ww * bf_lo(u[q].y); ax[3] += ww * bf_hi(u[q].y);
            ax[4] += ww * bf_lo(u[q].z); ax[5] += ww * bf_hi(u[q].z);
            ax[6] += ww * bf_lo(u[q].w); ax[7] += ww * bf_hi(u[q].w);
        }
    }
    // combine the 4 edge-slot groups (lanes cl, cl+16, cl+32, cl+48 share columns)
#pragma unroll
    for (int j = 0; j < 8; ++j) {
        ax[j] += __shfl_xor(ax[j], 16);
        ax[j] += __shfl_xor(ax[j], 32);
    }
    if (g == 0) {
        float dn = dis[node], di = dinv[node];
        uint4 un = *(const uint4*)(base + ((size_t)node << 8));
        float hs[8] = {bf_lo(un.x), bf_hi(un.x), bf_lo(un.y), bf_hi(un.y),
                       bf_lo(un.z), bf_hi(un.z), bf_lo(un.w), bf_hi(un.w)};
        int c0 = cl * 8;
        float4 bv0 = *(const float4*)&bias[c0];
        float4 bv1 = *(const float4*)&bias[c0 + 4];
        float bb[8] = {bv0.x, bv0.y, bv0.z, bv0.w, bv1.x, bv1.y, bv1.z, bv1.w};
        float o[8];
#pragma unroll
        for (int j = 0; j < 8; ++j)
            o[j] = fmaxf(ax[j] * dn + hs[j] * di + bb[j], 0.f);
        if (LAST) {
            *(float4*)&out[(size_t)node * D_HID + c0]     = make_float4(o[0], o[1], o[2], o[3]);
            *(float4*)&out[(size_t)node * D_HID + c0 + 4] = make_float4(o[4], o[5], o[6], o[7]);
        } else {
            uint4 p;
            p.x = (uint)f2bf(o[0]) | ((uint)f2bf(o[1]) << 16);
            p.y = (uint)f2bf(o[2]) | ((uint)f2bf(o[3]) << 16);
            p.z = (uint)f2bf(o[4]) | ((uint)f2bf(o[5]) << 16);
            p.w = (uint)f2bf(o[6]) | ((uint)f2bf(o[7]) << 16);
            *(uint4*)((char*)act + ((size_t)node << 8) + (cl << 4)) = p;
        }
    }
}

extern "C" void kernel_launch(void* const* d_in, const int* in_sizes, int n_in,
                              void* d_out, int out_size, void* d_ws, size_t ws_size,
                              hipStream_t stream) {
    const float* x  = (const float*)d_in[0];
    const int*   ei = (const int*)d_in[1];
    const float* W0 = (const float*)d_in[2];
    const float* b0 = (const float*)d_in[3];
    const float* W1 = (const float*)d_in[4];
    const float* b1 = (const float*)d_in[5];
    const float* W2 = (const float*)d_in[6];
    const float* b2 = (const float*)d_in[7];
    float* out = (float*)d_out;

    const int N = N_NODES, E = N_EDGES;
    const int* src = ei;
    const int* dst = ei + E;

    char* w = (char*)d_ws;
    size_t off = 0;
    auto alloc = [&](size_t bytes) {
        size_t o = off;
        off += (bytes + 255) & ~(size_t)255;
        return o;
    };
    int*    cnt    = (int*)(w + alloc((size_t)N * 4));
    int*    cursor = (int*)(w + alloc((size_t)N * 4));
    float*  dis    = (float*)(w + alloc((size_t)N * 4));
    float*  dinv   = (float*)(w + alloc((size_t)N * 4));
    int*    rp     = (int*)(w + alloc((size_t)(N + 1) * 4));
    int*    bsum   = (int*)(w + alloc((size_t)SCAN_NB * 4));
    int*    boff   = (int*)(w + alloc((size_t)SCAN_NB * 4));
    int*    col    = (int*)(w + alloc((size_t)E * 4));
    ushort* hb     = (ushort*)(w + alloc((size_t)N * D_HID * 2));
    ushort* act    = (ushort*)(w + alloc((size_t)N * D_HID * 2));
    ushort* Wt0    = (ushort*)(w + alloc((size_t)128 * 256 * 2));
    ushort* Wt1    = (ushort*)(w + alloc((size_t)128 * 128 * 2));
    ushort* Wt2    = (ushort*)(w + alloc((size_t)128 * 128 * 2));
    (void)ws_size; (void)n_in; (void)in_sizes; (void)out_size;

    hipMemsetAsync(cnt, 0, (size_t)N * 4, stream);

    deg_count_k<<<(E + 255) / 256, 256, 0, stream>>>(dst, cnt, E);
    bsum_k<<<SCAN_NB, 256, 0, stream>>>(cnt, bsum, N);
    bscan_k<<<1, 256, 0, stream>>>(bsum, boff, rp + N, SCAN_NB);
    scan3_k<<<SCAN_NB, 256, 0, stream>>>(cnt, boff, rp, dis, dinv, cursor, N);
    scatter_k<<<(E + 255) / 256, 256, 0, stream>>>(src, dst, rp, cursor, col, E);
    sortrow_k<<<(N + 3) / 4, 256, 0, stream>>>(rp, col, N);   // canonical order -> determinism

    wtrans_all_k<<<256, 256, 0, stream>>>(W0, W1, W2, Wt0, Wt1, Wt2);

    const int GG = 768;
    int nt256 = (N + 15) / 16;   // 3125
    int nt128 = (N + 31) / 32;   // 1563
    int agg_grid = (N + 3) / 4;

    // layer 0
    mfma_gemm_k<256, true><<<GG, 256, 0, stream>>>(x, Wt0, hb, N, nt256);
    aggregate_k<false><<<agg_grid, 256, 0, stream>>>(hb, rp, col, dis, dinv, b0, act, out, N);
    // layer 1
    mfma_gemm_k<128, false><<<GG, 256, 0, stream>>>(act, Wt1, hb, N, nt128);
    aggregate_k<false><<<agg_grid, 256, 0, stream>>>(hb, rp, col, dis, dinv, b1, act, out, N);
    // layer 2
    mfma_gemm_k<128, false><<<GG, 256, 0, stream>>>(act, Wt2, hb, N, nt128);
    aggregate_k<true><<<agg_grid, 256, 0, stream>>>(hb, rp, col, dis, dinv, b2, act, out, N);
}

// Round 9
// 276.851 us; speedup vs baseline: 1.0544x; 1.0544x over previous
//
#include <hip/hip_runtime.h>

#define N_NODES 50000
#define N_EDGES 800000
#define D_HID   128

typedef unsigned int uint;
typedef unsigned short ushort;
typedef __attribute__((ext_vector_type(8))) short short8;
typedef __attribute__((ext_vector_type(4))) float f32x4;

#define SCAN_NB ((N_NODES + 255) / 256)   // 196
#define NB       196                       // dst buckets of 256 nodes
#define CAP      6144                      // per-bucket ebuf capacity (mean 4096, +32 sigma)
#define P1_BLOCKS 200
#define P1_CHUNK  4000                     // 200 * 4000 = 800000 exactly

// ---------------- P1: partition edges into dst-range buckets ----------------
__global__ __launch_bounds__(256) void part_k(const int* __restrict__ src,
                                              const int* __restrict__ dst,
                                              int* __restrict__ bcur,
                                              int2* __restrict__ ebuf, int e) {
    __shared__ int hist[NB];
    __shared__ int base[NB];
    int tid = threadIdx.x;
    if (tid < NB) hist[tid] = 0;
    __syncthreads();

    int e0 = blockIdx.x * P1_CHUNK;
    int2 ed[16];
    bool val[16];
#pragma unroll
    for (int i = 0; i < 16; ++i) {
        int o = i * 256 + tid;
        int idx = e0 + o;
        val[i] = (o < P1_CHUNK) && (idx < e);
        if (val[i]) {
            ed[i] = make_int2(src[idx], dst[idx]);
            atomicAdd(&hist[ed[i].y >> 8], 1);
        }
    }
    __syncthreads();
    if (tid < NB && hist[tid] > 0) base[tid] = atomicAdd(&bcur[tid], hist[tid]);
    __syncthreads();
    if (tid < NB) hist[tid] = 0;
    __syncthreads();
#pragma unroll
    for (int i = 0; i < 16; ++i) {
        if (val[i]) {
            int bk = ed[i].y >> 8;
            int o  = base[bk] + atomicAdd(&hist[bk], 1);
            if (o < CAP) ebuf[(size_t)bk * CAP + o] = ed[i];
        }
    }
}

// ---------------- P2: per-bucket degree count (LDS atomics) ----------------
__global__ __launch_bounds__(256) void bucket_cnt_k(const int2* __restrict__ ebuf,
                                                    const int* __restrict__ bcnt,
                                                    int* __restrict__ cnt, int n) {
    __shared__ int c[256];
    int b = blockIdx.x, tid = threadIdx.x;
    c[tid] = 0;
    __syncthreads();
    int m = bcnt[b]; if (m > CAP) m = CAP;
    for (int i = tid; i < m; i += 256)
        atomicAdd(&c[ebuf[(size_t)b * CAP + i].y & 255], 1);
    __syncthreads();
    int node = b * 256 + tid;
    if (node < n) cnt[node] = c[tid];
}

// ---------------- 3-phase multi-block exclusive scan ----------------
__global__ void bsum_k(const int* __restrict__ cnt, int* __restrict__ bsum, int n) {
    int i = blockIdx.x * 256 + threadIdx.x;
    int v = (i < n) ? cnt[i] : 0;
#pragma unroll
    for (int off = 32; off; off >>= 1) v += __shfl_down(v, off, 64);
    __shared__ int ws[4];
    int lane = threadIdx.x & 63, w = threadIdx.x >> 6;
    if (lane == 0) ws[w] = v;
    __syncthreads();
    if (threadIdx.x == 0) bsum[blockIdx.x] = ws[0] + ws[1] + ws[2] + ws[3];
}

__global__ void bscan_k(const int* __restrict__ bsum, int* __restrict__ boff,
                        int* __restrict__ row_ptr_end, int nb) {
    __shared__ int s[256];
    int t = threadIdx.x;
    int v = (t < nb) ? bsum[t] : 0;
    s[t] = v;
    __syncthreads();
    for (int off = 1; off < 256; off <<= 1) {
        int u = (t >= off) ? s[t - off] : 0;
        __syncthreads();
        s[t] += u;
        __syncthreads();
    }
    if (t < nb) boff[t] = s[t] - v;        // exclusive
    if (t == 255) *row_ptr_end = s[255];   // total -> row_ptr[n]
}

// scan + fused degree-norm
__global__ void scan3_k(const int* __restrict__ cnt, const int* __restrict__ boff,
                        int* __restrict__ row_ptr, float* __restrict__ dis,
                        float* __restrict__ dinv, int n) {
    __shared__ int s[256];
    int i = blockIdx.x * 256 + threadIdx.x;
    int t = threadIdx.x;
    int v = (i < n) ? cnt[i] : 0;
    s[t] = v;
    __syncthreads();
    for (int off = 1; off < 256; off <<= 1) {
        int u = (t >= off) ? s[t - off] : 0;
        __syncthreads();
        s[t] += u;
        __syncthreads();
    }
    if (i < n) {
        row_ptr[i] = boff[blockIdx.x] + s[t] - v;
        float d = (float)v + 1.0f;
        dis[i]  = rsqrtf(d);
        dinv[i] = 1.0f / d;
    }
}

// ---------------- P3: per-bucket CSR scatter + fused row sort (canonical order) ----------------
__global__ __launch_bounds__(256) void csr_k(const int2* __restrict__ ebuf,
                                             const int* __restrict__ bcnt,
                                             const int* __restrict__ row_ptr,
                                             int* __restrict__ col, int n) {
    __shared__ int rp_l[257];
    __shared__ int cur[256];
    __shared__ int win[CAP];
    int b = blockIdx.x, tid = threadIdx.x;
    int node0 = b * 256;
    for (int i = tid; i < 257; i += 256) {
        int nd = node0 + i; if (nd > n) nd = n;
        rp_l[i] = row_ptr[nd];
    }
    cur[tid] = 0;
    __syncthreads();
    int base0 = rp_l[0];
    int m = bcnt[b]; if (m > CAP) m = CAP;

    for (int i = tid; i < m; i += 256) {
        int2 ed = ebuf[(size_t)b * CAP + i];
        int ll = ed.y & 255;
        int pos = rp_l[ll] + atomicAdd(&cur[ll], 1) - base0;
        win[pos] = ed.x;
    }
    __syncthreads();

    // sort each row segment in LDS (wave per row)
    int w = tid >> 6, lane = tid & 63;
    for (int r = w; r < 256; r += 4) {
        if (node0 + r >= n) break;
        int rb = rp_l[r] - base0, re = rp_l[r + 1] - base0;
        int len = re - rb;
        if (len <= 1) continue;
        if (len <= 64) {
            int v = (lane < len) ? win[rb + lane] : 0x7fffffff;
            for (int k = 2; k <= 64; k <<= 1)
                for (int j = k >> 1; j > 0; j >>= 1) {
                    int other = __shfl_xor(v, j);
                    bool up    = (lane & k) == 0;
                    bool small = (lane & j) == 0;
                    v = (small == up) ? min(v, other) : max(v, other);
                }
            if (lane < len) win[rb + lane] = v;
        } else if (lane == 0) {
            for (int i = rb + 1; i < re; ++i) {
                int key = win[i]; int j = i - 1;
                while (j >= rb && win[j] > key) { win[j + 1] = win[j]; --j; }
                win[j + 1] = key;
            }
        }
    }
    __syncthreads();
    for (int i = tid; i < m; i += 256) col[base0 + i] = win[i];
}

// ---- fp32 -> bf16 (RTNE) ----
__device__ inline ushort f2bf(float f) {
    unsigned u = __float_as_uint(f);
    unsigned rounding = 0x7fffu + ((u >> 16) & 1u);
    return (ushort)((u + rounding) >> 16);
}
__device__ inline float bf_lo(uint v) { return __uint_as_float(v << 16); }
__device__ inline float bf_hi(uint v) { return __uint_as_float(v & 0xffff0000u); }
__device__ inline short8 cvt8(float4 f0, float4 f1) {
    short8 r;
    r[0] = (short)f2bf(f0.x); r[1] = (short)f2bf(f0.y);
    r[2] = (short)f2bf(f0.z); r[3] = (short)f2bf(f0.w);
    r[4] = (short)f2bf(f1.x); r[5] = (short)f2bf(f1.y);
    r[6] = (short)f2bf(f1.z); r[7] = (short)f2bf(f1.w);
    return r;
}

// ---------------- all three W[K][128] fp32 -> Wt[128][K] bf16, one launch ----------------
__global__ void wtrans_all_k(const float* __restrict__ W0, const float* __restrict__ W1,
                             const float* __restrict__ W2, ushort* __restrict__ Wt0,
                             ushort* __restrict__ Wt1, ushort* __restrict__ Wt2) {
    int i = blockIdx.x * 256 + threadIdx.x;   // 0..65535
    const float* W; ushort* Wt; int K, j;
    if (i < 32768)      { W = W0; Wt = Wt0; K = 256; j = i; }
    else if (i < 49152) { W = W1; Wt = Wt1; K = 128; j = i - 32768; }
    else                { W = W2; Wt = Wt2; K = 128; j = i - 49152; }
    int k = j >> 7, n = j & 127;
    Wt[(size_t)n * K + k] = f2bf(W[j]);
}

// ---------------- MFMA GEMM, register-resident B, tile loop + A prefetch ----------------
// K=128: tile 32 rows; wave: rows (w>>1)*16, cols (w&1)*64 (NC=4, T=4)
// K=256: tile 16 rows; wave: all rows, cols w*32 (NC=2, T=8)
template<int K, bool AF32>
__global__ __launch_bounds__(256, 3) void mfma_gemm_k(const void* __restrict__ Ap,
                                                      const ushort* __restrict__ Bt, // [128][K]
                                                      ushort* __restrict__ H,        // [M][128]
                                                      int M, int ntiles) {
    constexpr int T   = K / 32;
    constexpr int NC  = (K == 128) ? 4 : 2;
    constexpr int RPT = (K == 128) ? 32 : 16;
    int tid = threadIdx.x;
    int w = tid >> 6, l = tid & 63;
    int lr = l & 15, kg = (l >> 4) * 8;
    int rIn   = (K == 128) ? (w >> 1) * 16 : 0;
    int cBase = (K == 128) ? (w & 1) * 64 : w * 32;

    short8 b[NC][T];
#pragma unroll
    for (int c = 0; c < NC; ++c)
#pragma unroll
        for (int t = 0; t < T; ++t)
            b[c][t] = *(const short8*)&Bt[(size_t)(cBase + c * 16 + lr) * K + t * 32 + kg];

    int tile = blockIdx.x;
    if (tile >= ntiles) return;
    const int G = gridDim.x;

    auto loadA = [&](int tl, short8* dst) {
        int rc = tl * RPT + rIn + lr; if (rc >= M) rc = M - 1;
        if constexpr (AF32) {
            const float* A32 = (const float*)Ap;
#pragma unroll
            for (int t = 0; t < T; ++t) {
                float4 f0 = *(const float4*)&A32[(size_t)rc * K + t * 32 + kg];
                float4 f1 = *(const float4*)&A32[(size_t)rc * K + t * 32 + kg + 4];
                dst[t] = cvt8(f0, f1);
            }
        } else {
            const ushort* A16 = (const ushort*)Ap;
#pragma unroll
            for (int t = 0; t < T; ++t)
                dst[t] = *(const short8*)&A16[(size_t)rc * K + t * 32 + kg];
        }
    };

    short8 a[T];
    loadA(tile, a);
    for (; tile < ntiles; tile += G) {
        short8 an[T];
        int nt = tile + G;
        if (nt < ntiles) loadA(nt, an);          // prefetch next tile's A

        f32x4 acc[NC];
#pragma unroll
        for (int c = 0; c < NC; ++c) acc[c] = (f32x4){0.f, 0.f, 0.f, 0.f};
#pragma unroll
        for (int t = 0; t < T; ++t)
#pragma unroll
            for (int c = 0; c < NC; ++c)
                acc[c] = __builtin_amdgcn_mfma_f32_16x16x32_bf16(a[t], b[c][t], acc[c], 0, 0, 0);

        int rs = tile * RPT + rIn + (l >> 4) * 4;
#pragma unroll
        for (int c = 0; c < NC; ++c)
#pragma unroll
            for (int j = 0; j < 4; ++j) {
                int r = rs + j;
                if (r < M) H[(size_t)r * 128 + cBase + c * 16 + lr] = f2bf(acc[c][j]);
            }
#pragma unroll
        for (int t = 0; t < T; ++t) a[t] = an[t];
    }
}

// ---------------- aggregate: relu(dis[n]*sum_e(dis[s]*hb[s]) + hb[n]*dinv[n] + b) ----------------
template<bool LAST>
__global__ __launch_bounds__(256) void aggregate_k(const ushort* __restrict__ hb,
                                                   const int* __restrict__ row_ptr,
                                                   const int* __restrict__ col,
                                                   const float* __restrict__ dis,
                                                   const float* __restrict__ dinv,
                                                   const float* __restrict__ bias,
                                                   ushort* __restrict__ act,
                                                   float* __restrict__ out, int n) {
    int node = blockIdx.x * 4 + (threadIdx.x >> 6);
    if (node >= n) return;
    int lane = threadIdx.x & 63;
    int g  = lane >> 4;          // edge-slot group 0..3
    int cl = lane & 15;          // column block: cols [8*cl, 8*cl+8)
    const char* base = (const char*)hb + (cl << 4);

    float ax[8];
#pragma unroll
    for (int j = 0; j < 8; ++j) ax[j] = 0.f;

    int beg = row_ptr[node], end = row_ptr[node + 1];
    for (int e = beg; e < end; e += 16) {
        int s[4]; float wv[4];
#pragma unroll
        for (int q = 0; q < 4; ++q) {
            int idx = e + q * 4 + g;
            bool v  = idx < end;
            s[q]  = col[v ? idx : (end - 1)];
            wv[q] = v ? dis[s[q]] : 0.f;
        }
        uint4 u[4];
#pragma unroll
        for (int q = 0; q < 4; ++q)
            u[q] = *(const uint4*)(base + ((size_t)s[q] << 8));
#pragma unroll
        for (int q = 0; q < 4; ++q) {
            float ww = wv[q];
            ax[0] += ww * bf_lo(u[q].x); ax[1] += ww * bf_hi(u[q].x);
            ax[2] += ww * bf_lo(u[q].y); ax[3] += ww * bf_hi(u[q].y);
            ax[4] += ww * bf_lo(u[q].z); ax[5] += ww * bf_hi(u[q].z);
            ax[6] += ww * bf_lo(u[q].w); ax[7] += ww * bf_hi(u[q].w);
        }
    }
#pragma unroll
    for (int j = 0; j < 8; ++j) {
        ax[j] += __shfl_xor(ax[j], 16);
        ax[j] += __shfl_xor(ax[j], 32);
    }
    if (g == 0) {
        float dn = dis[node], di = dinv[node];
        uint4 un = *(const uint4*)(base + ((size_t)node << 8));
        float hs[8] = {bf_lo(un.x), bf_hi(un.x), bf_lo(un.y), bf_hi(un.y),
                       bf_lo(un.z), bf_hi(un.z), bf_lo(un.w), bf_hi(un.w)};
        int c0 = cl * 8;
        float4 bv0 = *(const float4*)&bias[c0];
        float4 bv1 = *(const float4*)&bias[c0 + 4];
        float bb[8] = {bv0.x, bv0.y, bv0.z, bv0.w, bv1.x, bv1.y, bv1.z, bv1.w};
        float o[8];
#pragma unroll
        for (int j = 0; j < 8; ++j)
            o[j] = fmaxf(ax[j] * dn + hs[j] * di + bb[j], 0.f);
        if (LAST) {
            *(float4*)&out[(size_t)node * D_HID + c0]     = make_float4(o[0], o[1], o[2], o[3]);
            *(float4*)&out[(size_t)node * D_HID + c0 + 4] = make_float4(o[4], o[5], o[6], o[7]);
        } else {
            uint4 p;
            p.x = (uint)f2bf(o[0]) | ((uint)f2bf(o[1]) << 16);
            p.y = (uint)f2bf(o[2]) | ((uint)f2bf(o[3]) << 16);
            p.z = (uint)f2bf(o[4]) | ((uint)f2bf(o[5]) << 16);
            p.w = (uint)f2bf(o[6]) | ((uint)f2bf(o[7]) << 16);
            *(uint4*)((char*)act + ((size_t)node << 8) + (cl << 4)) = p;
        }
    }
}

extern "C" void kernel_launch(void* const* d_in, const int* in_sizes, int n_in,
                              void* d_out, int out_size, void* d_ws, size_t ws_size,
                              hipStream_t stream) {
    const float* x  = (const float*)d_in[0];
    const int*   ei = (const int*)d_in[1];
    const float* W0 = (const float*)d_in[2];
    const float* b0 = (const float*)d_in[3];
    const float* W1 = (const float*)d_in[4];
    const float* b1 = (const float*)d_in[5];
    const float* W2 = (const float*)d_in[6];
    const float* b2 = (const float*)d_in[7];
    float* out = (float*)d_out;

    const int N = N_NODES, E = N_EDGES;
    const int* src = ei;
    const int* dst = ei + E;

    char* w = (char*)d_ws;
    size_t off = 0;
    auto alloc = [&](size_t bytes) {
        size_t o = off;
        off += (bytes + 255) & ~(size_t)255;
        return o;
    };
    int*    cnt    = (int*)(w + alloc((size_t)N * 4));
    int*    bcur   = (int*)(w + alloc((size_t)NB * 4));
    float*  dis    = (float*)(w + alloc((size_t)N * 4));
    float*  dinv   = (float*)(w + alloc((size_t)N * 4));
    int*    rp     = (int*)(w + alloc((size_t)(N + 1) * 4));
    int*    bsum   = (int*)(w + alloc((size_t)SCAN_NB * 4));
    int*    boff   = (int*)(w + alloc((size_t)SCAN_NB * 4));
    int*    col    = (int*)(w + alloc((size_t)E * 4));
    int2*   ebuf   = (int2*)(w + alloc((size_t)NB * CAP * 8));
    ushort* hb     = (ushort*)(w + alloc((size_t)N * D_HID * 2));
    ushort* act    = (ushort*)(w + alloc((size_t)N * D_HID * 2));
    ushort* Wt0    = (ushort*)(w + alloc((size_t)128 * 256 * 2));
    ushort* Wt1    = (ushort*)(w + alloc((size_t)128 * 128 * 2));
    ushort* Wt2    = (ushort*)(w + alloc((size_t)128 * 128 * 2));
    (void)ws_size; (void)n_in; (void)in_sizes; (void)out_size;

    hipMemsetAsync(bcur, 0, (size_t)NB * 4, stream);

    part_k<<<P1_BLOCKS, 256, 0, stream>>>(src, dst, bcur, ebuf, E);
    bucket_cnt_k<<<NB, 256, 0, stream>>>(ebuf, bcur, cnt, N);
    bsum_k<<<SCAN_NB, 256, 0, stream>>>(cnt, bsum, N);
    bscan_k<<<1, 256, 0, stream>>>(bsum, boff, rp + N, SCAN_NB);
    scan3_k<<<SCAN_NB, 256, 0, stream>>>(cnt, boff, rp, dis, dinv, N);
    csr_k<<<NB, 256, 0, stream>>>(ebuf, bcur, rp, col, N);

    wtrans_all_k<<<256, 256, 0, stream>>>(W0, W1, W2, Wt0, Wt1, Wt2);

    const int GG = 768;
    int nt256 = (N + 15) / 16;   // 3125
    int nt128 = (N + 31) / 32;   // 1563
    int agg_grid = (N + 3) / 4;

    // layer 0
    mfma_gemm_k<256, true><<<GG, 256, 0, stream>>>(x, Wt0, hb, N, nt256);
    aggregate_k<false><<<agg_grid, 256, 0, stream>>>(hb, rp, col, dis, dinv, b0, act, out, N);
    // layer 1
    mfma_gemm_k<128, false><<<GG, 256, 0, stream>>>(act, Wt1, hb, N, nt128);
    aggregate_k<false><<<agg_grid, 256, 0, stream>>>(hb, rp, col, dis, dinv, b1, act, out, N);
    // layer 2
    mfma_gemm_k<128, false><<<GG, 256, 0, stream>>>(act, Wt2, hb, N, nt128);
    aggregate_k<true><<<agg_grid, 256, 0, stream>>>(hb, rp, col, dis, dinv, b2, act, out, N);
}

// Round 10
// 235.771 us; speedup vs baseline: 1.2381x; 1.1742x over previous
//
#include <hip/hip_runtime.h>

#define N_NODES 50000
#define N_EDGES 800000
#define D_HID   128

typedef unsigned int uint;
typedef unsigned short ushort;
typedef __attribute__((ext_vector_type(8))) short short8;
typedef __attribute__((ext_vector_type(4))) float f32x4;

#define SCAN_NB ((N_NODES + 255) / 256)   // 196
#define NB       196                       // dst buckets of 256 nodes
#define CAP      6144                      // per-bucket ebuf capacity (mean 4096, +32 sigma)
#define P1_BLOCKS 200
#define P1_CHUNK  4000                     // 200 * 4000 = 800000 exactly

// ---------------- P1: partition edges into dst-range buckets ----------------
__global__ __launch_bounds__(256) void part_k(const int* __restrict__ src,
                                              const int* __restrict__ dst,
                                              int* __restrict__ bcur,
                                              int2* __restrict__ ebuf, int e) {
    __shared__ int hist[NB];
    __shared__ int base[NB];
    int tid = threadIdx.x;
    if (tid < NB) hist[tid] = 0;
    __syncthreads();

    int e0 = blockIdx.x * P1_CHUNK;
    int2 ed[16];
    bool val[16];
#pragma unroll
    for (int i = 0; i < 16; ++i) {
        int o = i * 256 + tid;
        int idx = e0 + o;
        val[i] = (o < P1_CHUNK) && (idx < e);
        if (val[i]) {
            ed[i] = make_int2(src[idx], dst[idx]);
            atomicAdd(&hist[ed[i].y >> 8], 1);
        }
    }
    __syncthreads();
    if (tid < NB && hist[tid] > 0) base[tid] = atomicAdd(&bcur[tid], hist[tid]);
    __syncthreads();
    if (tid < NB) hist[tid] = 0;
    __syncthreads();
#pragma unroll
    for (int i = 0; i < 16; ++i) {
        if (val[i]) {
            int bk = ed[i].y >> 8;
            int o  = base[bk] + atomicAdd(&hist[bk], 1);
            if (o < CAP) ebuf[(size_t)bk * CAP + o] = ed[i];
        }
    }
}

// ---------------- P2: per-bucket degree count (LDS atomics) ----------------
__global__ __launch_bounds__(256) void bucket_cnt_k(const int2* __restrict__ ebuf,
                                                    const int* __restrict__ bcnt,
                                                    int* __restrict__ cnt, int n) {
    __shared__ int c[256];
    int b = blockIdx.x, tid = threadIdx.x;
    c[tid] = 0;
    __syncthreads();
    int m = bcnt[b]; if (m > CAP) m = CAP;
    for (int i = tid; i < m; i += 256)
        atomicAdd(&c[ebuf[(size_t)b * CAP + i].y & 255], 1);
    __syncthreads();
    int node = b * 256 + tid;
    if (node < n) cnt[node] = c[tid];
}

// ---------------- 3-phase multi-block exclusive scan ----------------
__global__ void bsum_k(const int* __restrict__ cnt, int* __restrict__ bsum, int n) {
    int i = blockIdx.x * 256 + threadIdx.x;
    int v = (i < n) ? cnt[i] : 0;
#pragma unroll
    for (int off = 32; off; off >>= 1) v += __shfl_down(v, off, 64);
    __shared__ int ws[4];
    int lane = threadIdx.x & 63, w = threadIdx.x >> 6;
    if (lane == 0) ws[w] = v;
    __syncthreads();
    if (threadIdx.x == 0) bsum[blockIdx.x] = ws[0] + ws[1] + ws[2] + ws[3];
}

__global__ void bscan_k(const int* __restrict__ bsum, int* __restrict__ boff,
                        int* __restrict__ row_ptr_end, int nb) {
    __shared__ int s[256];
    int t = threadIdx.x;
    int v = (t < nb) ? bsum[t] : 0;
    s[t] = v;
    __syncthreads();
    for (int off = 1; off < 256; off <<= 1) {
        int u = (t >= off) ? s[t - off] : 0;
        __syncthreads();
        s[t] += u;
        __syncthreads();
    }
    if (t < nb) boff[t] = s[t] - v;        // exclusive
    if (t == 255) *row_ptr_end = s[255];   // total -> row_ptr[n]
}

// scan + fused degree-norm
__global__ void scan3_k(const int* __restrict__ cnt, const int* __restrict__ boff,
                        int* __restrict__ row_ptr, float* __restrict__ dis,
                        float* __restrict__ dinv, int n) {
    __shared__ int s[256];
    int i = blockIdx.x * 256 + threadIdx.x;
    int t = threadIdx.x;
    int v = (i < n) ? cnt[i] : 0;
    s[t] = v;
    __syncthreads();
    for (int off = 1; off < 256; off <<= 1) {
        int u = (t >= off) ? s[t - off] : 0;
        __syncthreads();
        s[t] += u;
        __syncthreads();
    }
    if (i < n) {
        row_ptr[i] = boff[blockIdx.x] + s[t] - v;
        float d = (float)v + 1.0f;
        dis[i]  = rsqrtf(d);
        dinv[i] = 1.0f / d;
    }
}

// ---------------- P3: per-bucket CSR scatter via LDS window (coalesced dump) ----------------
__global__ __launch_bounds__(256) void csr_k(const int2* __restrict__ ebuf,
                                             const int* __restrict__ bcnt,
                                             const int* __restrict__ row_ptr,
                                             int* __restrict__ col, int n) {
    __shared__ int rp_l[257];
    __shared__ int cur[256];
    __shared__ int win[CAP];
    int b = blockIdx.x, tid = threadIdx.x;
    int node0 = b * 256;
    for (int i = tid; i < 257; i += 256) {
        int nd = node0 + i; if (nd > n) nd = n;
        rp_l[i] = row_ptr[nd];
    }
    cur[tid] = 0;
    __syncthreads();
    int base0 = rp_l[0];
    int m = bcnt[b]; if (m > CAP) m = CAP;

    for (int i = tid; i < m; i += 256) {
        int2 ed = ebuf[(size_t)b * CAP + i];
        int ll = ed.y & 255;
        int pos = rp_l[ll] + atomicAdd(&cur[ll], 1) - base0;
        win[pos] = ed.x;
    }
    __syncthreads();
    for (int i = tid; i < m; i += 256) col[base0 + i] = win[i];
}

// ---------------- canonicalize: wave-per-row sort (wide grid) ----------------
// Sorted rows are a canonical multiset representation -> downstream fp32 sums
// are bit-deterministic call-to-call despite nondeterministic atomic scatter.
__global__ __launch_bounds__(256) void rowsort_k(const int* __restrict__ rp,
                                                 int* __restrict__ col, int n) {
    int node = blockIdx.x * 4 + (threadIdx.x >> 6);
    if (node >= n) return;
    int lane = threadIdx.x & 63;
    int beg = rp[node], end = rp[node + 1];
    int len = end - beg;
    if (len <= 1) return;
    if (len <= 64) {
        int v = (lane < len) ? col[beg + lane] : 0x7fffffff;
#pragma unroll
        for (int k = 2; k <= 64; k <<= 1)
#pragma unroll
            for (int j = k >> 1; j > 0; j >>= 1) {
                int other = __shfl_xor(v, j);
                bool up    = (lane & k) == 0;
                bool small = (lane & j) == 0;
                v = (small == up) ? min(v, other) : max(v, other);
            }
        if (lane < len) col[beg + lane] = v;
    } else if (lane == 0) {     // rare tail: serial insertion sort
        for (int i = beg + 1; i < end; ++i) {
            int key = col[i]; int j = i - 1;
            while (j >= beg && col[j] > key) { col[j + 1] = col[j]; --j; }
            col[j + 1] = key;
        }
    }
}

// ---- fp32 -> bf16 (RTNE) ----
__device__ inline ushort f2bf(float f) {
    unsigned u = __float_as_uint(f);
    unsigned rounding = 0x7fffu + ((u >> 16) & 1u);
    return (ushort)((u + rounding) >> 16);
}
__device__ inline float bf_lo(uint v) { return __uint_as_float(v << 16); }
__device__ inline float bf_hi(uint v) { return __uint_as_float(v & 0xffff0000u); }
__device__ inline short8 cvt8(float4 f0, float4 f1) {
    short8 r;
    r[0] = (short)f2bf(f0.x); r[1] = (short)f2bf(f0.y);
    r[2] = (short)f2bf(f0.z); r[3] = (short)f2bf(f0.w);
    r[4] = (short)f2bf(f1.x); r[5] = (short)f2bf(f1.y);
    r[6] = (short)f2bf(f1.z); r[7] = (short)f2bf(f1.w);
    return r;
}

// ---------------- all three W[K][128] fp32 -> Wt[128][K] bf16, one launch ----------------
__global__ void wtrans_all_k(const float* __restrict__ W0, const float* __restrict__ W1,
                             const float* __restrict__ W2, ushort* __restrict__ Wt0,
                             ushort* __restrict__ Wt1, ushort* __restrict__ Wt2) {
    int i = blockIdx.x * 256 + threadIdx.x;   // 0..65535
    const float* W; ushort* Wt; int K, j;
    if (i < 32768)      { W = W0; Wt = Wt0; K = 256; j = i; }
    else if (i < 49152) { W = W1; Wt = Wt1; K = 128; j = i - 32768; }
    else                { W = W2; Wt = Wt2; K = 128; j = i - 49152; }
    int k = j >> 7, n = j & 127;
    Wt[(size_t)n * K + k] = f2bf(W[j]);
}

// ---------------- MFMA GEMM, register-resident B, tile loop + A prefetch ----------------
// K=128: tile 32 rows; wave: rows (w>>1)*16, cols (w&1)*64 (NC=4, T=4)
// K=256: tile 16 rows; wave: all rows, cols w*32 (NC=2, T=8)
template<int K, bool AF32>
__global__ __launch_bounds__(256, 3) void mfma_gemm_k(const void* __restrict__ Ap,
                                                      const ushort* __restrict__ Bt, // [128][K]
                                                      ushort* __restrict__ H,        // [M][128]
                                                      int M, int ntiles) {
    constexpr int T   = K / 32;
    constexpr int NC  = (K == 128) ? 4 : 2;
    constexpr int RPT = (K == 128) ? 32 : 16;
    int tid = threadIdx.x;
    int w = tid >> 6, l = tid & 63;
    int lr = l & 15, kg = (l >> 4) * 8;
    int rIn   = (K == 128) ? (w >> 1) * 16 : 0;
    int cBase = (K == 128) ? (w & 1) * 64 : w * 32;

    short8 b[NC][T];
#pragma unroll
    for (int c = 0; c < NC; ++c)
#pragma unroll
        for (int t = 0; t < T; ++t)
            b[c][t] = *(const short8*)&Bt[(size_t)(cBase + c * 16 + lr) * K + t * 32 + kg];

    int tile = blockIdx.x;
    if (tile >= ntiles) return;
    const int G = gridDim.x;

    auto loadA = [&](int tl, short8* dst) {
        int rc = tl * RPT + rIn + lr; if (rc >= M) rc = M - 1;
        if constexpr (AF32) {
            const float* A32 = (const float*)Ap;
#pragma unroll
            for (int t = 0; t < T; ++t) {
                float4 f0 = *(const float4*)&A32[(size_t)rc * K + t * 32 + kg];
                float4 f1 = *(const float4*)&A32[(size_t)rc * K + t * 32 + kg + 4];
                dst[t] = cvt8(f0, f1);
            }
        } else {
            const ushort* A16 = (const ushort*)Ap;
#pragma unroll
            for (int t = 0; t < T; ++t)
                dst[t] = *(const short8*)&A16[(size_t)rc * K + t * 32 + kg];
        }
    };

    short8 a[T];
    loadA(tile, a);
    for (; tile < ntiles; tile += G) {
        short8 an[T];
        int nt = tile + G;
        if (nt < ntiles) loadA(nt, an);          // prefetch next tile's A

        f32x4 acc[NC];
#pragma unroll
        for (int c = 0; c < NC; ++c) acc[c] = (f32x4){0.f, 0.f, 0.f, 0.f};
#pragma unroll
        for (int t = 0; t < T; ++t)
#pragma unroll
            for (int c = 0; c < NC; ++c)
                acc[c] = __builtin_amdgcn_mfma_f32_16x16x32_bf16(a[t], b[c][t], acc[c], 0, 0, 0);

        int rs = tile * RPT + rIn + (l >> 4) * 4;
#pragma unroll
        for (int c = 0; c < NC; ++c)
#pragma unroll
            for (int j = 0; j < 4; ++j) {
                int r = rs + j;
                if (r < M) H[(size_t)r * 128 + cBase + c * 16 + lr] = f2bf(acc[c][j]);
            }
#pragma unroll
        for (int t = 0; t < T; ++t) a[t] = an[t];
    }
}

// ---------------- aggregate: relu(dis[n]*sum_e(dis[s]*hb[s]) + hb[n]*dinv[n] + b) ----------------
template<bool LAST>
__global__ __launch_bounds__(256) void aggregate_k(const ushort* __restrict__ hb,
                                                   const int* __restrict__ row_ptr,
                                                   const int* __restrict__ col,
                                                   const float* __restrict__ dis,
                                                   const float* __restrict__ dinv,
                                                   const float* __restrict__ bias,
                                                   ushort* __restrict__ act,
                                                   float* __restrict__ out, int n) {
    int node = blockIdx.x * 4 + (threadIdx.x >> 6);
    if (node >= n) return;
    int lane = threadIdx.x & 63;
    int g  = lane >> 4;          // edge-slot group 0..3
    int cl = lane & 15;          // column block: cols [8*cl, 8*cl+8)
    const char* base = (const char*)hb + (cl << 4);

    float ax[8];
#pragma unroll
    for (int j = 0; j < 8; ++j) ax[j] = 0.f;

    int beg = row_ptr[node], end = row_ptr[node + 1];
    for (int e = beg; e < end; e += 16) {
        int s[4]; float wv[4];
#pragma unroll
        for (int q = 0; q < 4; ++q) {
            int idx = e + q * 4 + g;
            bool v  = idx < end;
            s[q]  = col[v ? idx : (end - 1)];
            wv[q] = v ? dis[s[q]] : 0.f;
        }
        uint4 u[4];
#pragma unroll
        for (int q = 0; q < 4; ++q)
            u[q] = *(const uint4*)(base + ((size_t)s[q] << 8));
#pragma unroll
        for (int q = 0; q < 4; ++q) {
            float ww = wv[q];
            ax[0] += ww * bf_lo(u[q].x); ax[1] += ww * bf_hi(u[q].x);
            ax[2] += ww * bf_lo(u[q].y); ax[3] += ww * bf_hi(u[q].y);
            ax[4] += ww * bf_lo(u[q].z); ax[5] += ww * bf_hi(u[q].z);
            ax[6] += ww * bf_lo(u[q].w); ax[7] += ww * bf_hi(u[q].w);
        }
    }
#pragma unroll
    for (int j = 0; j < 8; ++j) {
        ax[j] += __shfl_xor(ax[j], 16);
        ax[j] += __shfl_xor(ax[j], 32);
    }
    if (g == 0) {
        float dn = dis[node], di = dinv[node];
        uint4 un = *(const uint4*)(base + ((size_t)node << 8));
        float hs[8] = {bf_lo(un.x), bf_hi(un.x), bf_lo(un.y), bf_hi(un.y),
                       bf_lo(un.z), bf_hi(un.z), bf_lo(un.w), bf_hi(un.w)};
        int c0 = cl * 8;
        float4 bv0 = *(const float4*)&bias[c0];
        float4 bv1 = *(const float4*)&bias[c0 + 4];
        float bb[8] = {bv0.x, bv0.y, bv0.z, bv0.w, bv1.x, bv1.y, bv1.z, bv1.w};
        float o[8];
#pragma unroll
        for (int j = 0; j < 8; ++j)
            o[j] = fmaxf(ax[j] * dn + hs[j] * di + bb[j], 0.f);
        if (LAST) {
            *(float4*)&out[(size_t)node * D_HID + c0]     = make_float4(o[0], o[1], o[2], o[3]);
            *(float4*)&out[(size_t)node * D_HID + c0 + 4] = make_float4(o[4], o[5], o[6], o[7]);
        } else {
            uint4 p;
            p.x = (uint)f2bf(o[0]) | ((uint)f2bf(o[1]) << 16);
            p.y = (uint)f2bf(o[2]) | ((uint)f2bf(o[3]) << 16);
            p.z = (uint)f2bf(o[4]) | ((uint)f2bf(o[5]) << 16);
            p.w = (uint)f2bf(o[6]) | ((uint)f2bf(o[7]) << 16);
            *(uint4*)((char*)act + ((size_t)node << 8) + (cl << 4)) = p;
        }
    }
}

extern "C" void kernel_launch(void* const* d_in, const int* in_sizes, int n_in,
                              void* d_out, int out_size, void* d_ws, size_t ws_size,
                              hipStream_t stream) {
    const float* x  = (const float*)d_in[0];
    const int*   ei = (const int*)d_in[1];
    const float* W0 = (const float*)d_in[2];
    const float* b0 = (const float*)d_in[3];
    const float* W1 = (const float*)d_in[4];
    const float* b1 = (const float*)d_in[5];
    const float* W2 = (const float*)d_in[6];
    const float* b2 = (const float*)d_in[7];
    float* out = (float*)d_out;

    const int N = N_NODES, E = N_EDGES;
    const int* src = ei;
    const int* dst = ei + E;

    char* w = (char*)d_ws;
    size_t off = 0;
    auto alloc = [&](size_t bytes) {
        size_t o = off;
        off += (bytes + 255) & ~(size_t)255;
        return o;
    };
    int*    cnt    = (int*)(w + alloc((size_t)N * 4));
    int*    bcur   = (int*)(w + alloc((size_t)NB * 4));
    float*  dis    = (float*)(w + alloc((size_t)N * 4));
    float*  dinv   = (float*)(w + alloc((size_t)N * 4));
    int*    rp     = (int*)(w + alloc((size_t)(N + 1) * 4));
    int*    bsum   = (int*)(w + alloc((size_t)SCAN_NB * 4));
    int*    boff   = (int*)(w + alloc((size_t)SCAN_NB * 4));
    int*    col    = (int*)(w + alloc((size_t)E * 4));
    int2*   ebuf   = (int2*)(w + alloc((size_t)NB * CAP * 8));
    ushort* hb     = (ushort*)(w + alloc((size_t)N * D_HID * 2));
    ushort* act    = (ushort*)(w + alloc((size_t)N * D_HID * 2));
    ushort* Wt0    = (ushort*)(w + alloc((size_t)128 * 256 * 2));
    ushort* Wt1    = (ushort*)(w + alloc((size_t)128 * 128 * 2));
    ushort* Wt2    = (ushort*)(w + alloc((size_t)128 * 128 * 2));
    (void)ws_size; (void)n_in; (void)in_sizes; (void)out_size;

    hipMemsetAsync(bcur, 0, (size_t)NB * 4, stream);

    part_k<<<P1_BLOCKS, 256, 0, stream>>>(src, dst, bcur, ebuf, E);
    bucket_cnt_k<<<NB, 256, 0, stream>>>(ebuf, bcur, cnt, N);
    bsum_k<<<SCAN_NB, 256, 0, stream>>>(cnt, bsum, N);
    bscan_k<<<1, 256, 0, stream>>>(bsum, boff, rp + N, SCAN_NB);
    scan3_k<<<SCAN_NB, 256, 0, stream>>>(cnt, boff, rp, dis, dinv, N);
    csr_k<<<NB, 256, 0, stream>>>(ebuf, bcur, rp, col, N);
    rowsort_k<<<(N + 3) / 4, 256, 0, stream>>>(rp, col, N);   // canonical order (wide)

    wtrans_all_k<<<256, 256, 0, stream>>>(W0, W1, W2, Wt0, Wt1, Wt2);

    const int GG = 768;
    int nt256 = (N + 15) / 16;   // 3125
    int nt128 = (N + 31) / 32;   // 1563
    int agg_grid = (N + 3) / 4;

    // layer 0
    mfma_gemm_k<256, true><<<GG, 256, 0, stream>>>(x, Wt0, hb, N, nt256);
    aggregate_k<false><<<agg_grid, 256, 0, stream>>>(hb, rp, col, dis, dinv, b0, act, out, N);
    // layer 1
    mfma_gemm_k<128, false><<<GG, 256, 0, stream>>>(act, Wt1, hb, N, nt128);
    aggregate_k<false><<<agg_grid, 256, 0, stream>>>(hb, rp, col, dis, dinv, b1, act, out, N);
    // layer 2
    mfma_gemm_k<128, false><<<GG, 256, 0, stream>>>(act, Wt2, hb, N, nt128);
    aggregate_k<true><<<agg_grid, 256, 0, stream>>>(hb, rp, col, dis, dinv, b2, act, out, N);
}